// Round 8
// baseline (227.011 us; speedup 1.0000x reference)
//
#include <hip/hip_runtime.h>
#include <hip/hip_bf16.h>

#define HIDDEN 4096
#define NHEADS 32
#define HDIM 128
#define CLEN 512
#define BATCH 32
#define KB 256   // keys per attention half-block (4 waves x 64 keys)

typedef float f32x4 __attribute__((ext_vector_type(4)));

// ---------------------------------------------------------------------------
// 4-row / 256-thread projection body (q-proj standalone, v-proj fused into
// the attention dispatch). Coalesced W streaming + butterfly reduction.
// Measured near the L3-warm weight-streaming floor (~14 us / 64 MB).
// ---------------------------------------------------------------------------
__device__ __forceinline__ void proj4_body(const float* __restrict__ X,
                                           const float* __restrict__ W,
                                           float* __restrict__ Y,
                                           int rowblock) {
    const int t   = threadIdx.x;
    const int l   = t & 63;
    const int wid = t >> 6;                      // 0..3 -> batch octet
    const int rowbase = rowblock * 4;
    const float* wp = W + (size_t)rowbase * HIDDEN + 4 * l;
    const float* xp = X + (size_t)(wid * 8) * HIDDEN + 4 * l;

    float v[32];
    #pragma unroll
    for (int j = 0; j < 32; ++j) v[j] = 0.f;

    #pragma unroll 2
    for (int kp = 0; kp < HIDDEN; kp += 256) {
        float4 wv[4], xv[8];
        #pragma unroll
        for (int r = 0; r < 4; ++r)
            wv[r] = *(const float4*)(wp + (size_t)r * HIDDEN + kp);
        #pragma unroll
        for (int b = 0; b < 8; ++b)
            xv[b] = *(const float4*)(xp + (size_t)b * HIDDEN + kp);
        #pragma unroll
        for (int r = 0; r < 4; ++r) {
            #pragma unroll
            for (int b = 0; b < 8; ++b) {
                v[r * 8 + b] += wv[r].x * xv[b].x + wv[r].y * xv[b].y +
                                wv[r].z * xv[b].z + wv[r].w * xv[b].w;
            }
        }
    }

    #pragma unroll
    for (int j = 0; j < 32; ++j) v[j] += __shfl_xor(v[j], 1);
    #pragma unroll
    for (int s = 1; s <= 5; ++s) {
        const int m = 1 << s;
        const int bit = (l >> s) & 1;
        #pragma unroll
        for (int i = 0; i < (32 >> s); ++i) {
            float t0 = __shfl_xor(v[2 * i], m);
            float t1 = __shfl_xor(v[2 * i + 1], m);
            v[i] = bit ? (v[2 * i + 1] + t1) : (v[2 * i] + t0);
        }
    }
    if (!(l & 1)) {
        const int j = l >> 1;                    // 0..31
        const int r = j >> 3, b = j & 7;
        Y[(size_t)(wid * 8 + b) * HIDDEN + rowbase + r] = v[0];
    }
}

__global__ __launch_bounds__(256) void proj_q_kernel(const float* __restrict__ X,
                                                     const float* __restrict__ W,
                                                     float* __restrict__ Y) {
    proj4_body(X, W, Y, blockIdx.x);
}

// ---------------------------------------------------------------------------
// Attention half-block: wave-local online-softmax flash over 64 keys/wave
// (zero barriers in the streaming loop), then a small LDS merge of the 4
// waves -> ONE (o[128], m, s) per half-block. The 2-way half merge happens
// inline in the fused out-projection.
// ---------------------------------------------------------------------------
__device__ __forceinline__ void attn_body(const float* __restrict__ q,
                                          const float* __restrict__ kc,
                                          const float* __restrict__ vc,
                                          float* __restrict__ o_half,   // [2048][128]
                                          float* __restrict__ ms,       // [2048]
                                          float* __restrict__ ss,       // [2048]
                                          int bid) {
    __shared__ float lo[4][HDIM];
    __shared__ float lm[4], lsw[4];
    const int t = threadIdx.x;
    const int w = t >> 6;                 // wave 0..3
    const int l = t & 63;
    const int bh = bid >> 1;
    const int half = bid & 1;
    const int b = bh >> 5, h = bh & 31;
    const float* K = kc + (size_t)bh * CLEN * HDIM + (size_t)(half * KB + w * 64) * HDIM;
    const float* V = vc + (size_t)bh * CLEN * HDIM + (size_t)(half * KB + w * 64) * HDIM;
    const float scale = 0.088388347648318447f;   // 1/sqrt(128)
    const int d0 = 4 * (l & 31);
    const int kh = l >> 5;                // half-wave key parity
    const int rot = (bid & 31) * 2;       // even stagger within the 64 keys
    f32x4 q4 = *(const f32x4*)(q + (size_t)b * HIDDEN + h * HDIM + d0);

    float mloc = -INFINITY, sloc = 0.f;
    f32x4 acc = {0.f, 0.f, 0.f, 0.f};

    #pragma unroll 4
    for (int r = 0; r < 32; ++r) {
        const int k = ((2 * r + rot) & 63) + kh;
        f32x4 kv = __builtin_nontemporal_load((const f32x4*)(K + (size_t)k * HDIM + d0));
        float p = q4.x * kv.x + q4.y * kv.y + q4.z * kv.z + q4.w * kv.w;
        #pragma unroll
        for (int m = 16; m; m >>= 1) p += __shfl_xor(p, m);  // 32-lane halves
        p *= scale;
        f32x4 vv = __builtin_nontemporal_load((const f32x4*)(V + (size_t)k * HDIM + d0));
        const float mn = fmaxf(mloc, p);
        const float c = __expf(mloc - mn);   // 0 on first round (mloc=-inf)
        const float e = __expf(p - mn);
        sloc = sloc * c + e;
        acc = acc * c + vv * e;
        mloc = mn;
    }

    // ---- merge the two half-wave streams (even vs odd keys) ----
    const float mo = __shfl_xor(mloc, 32);
    const float M = fmaxf(mloc, mo);
    const float wsc = __expf(mloc - M);
    float sw = sloc * wsc;
    sw += __shfl_xor(sw, 32);
    acc *= wsc;
    acc.x += __shfl_xor(acc.x, 32);
    acc.y += __shfl_xor(acc.y, 32);
    acc.z += __shfl_xor(acc.z, 32);
    acc.w += __shfl_xor(acc.w, 32);

    // ---- merge the 4 waves via LDS -> one (o, m, s) per half-block ----
    if (l < 32) *(f32x4*)(&lo[w][d0]) = acc;
    if (l == 0) { lm[w] = M; lsw[w] = sw; }
    __syncthreads();
    if (t < HDIM) {
        const float M4 = fmaxf(fmaxf(lm[0], lm[1]), fmaxf(lm[2], lm[3]));
        const float e0 = __expf(lm[0] - M4), e1 = __expf(lm[1] - M4);
        const float e2 = __expf(lm[2] - M4), e3 = __expf(lm[3] - M4);
        const float o = lo[0][t] * e0 + lo[1][t] * e1 + lo[2][t] * e2 + lo[3][t] * e3;
        o_half[(size_t)bid * HDIM + t] = o;
        if (t == 0) {
            ms[bid] = M4;
            ss[bid] = lsw[0] * e0 + lsw[1] * e1 + lsw[2] * e2 + lsw[3] * e3;
        }
    }
}

// ---------------------------------------------------------------------------
// Fused dispatch: 3072 blocks. bid%3==2 -> v-projection chunk (1024 blocks);
// else attention half-block (2048). proj_v rides in attention's BW slack.
// ---------------------------------------------------------------------------
__global__ __launch_bounds__(256, 4) void attn_projv_kernel(
        const float* __restrict__ q, const float* __restrict__ kc,
        const float* __restrict__ vc, const float* __restrict__ x,
        const float* __restrict__ wv_m, float* __restrict__ vnew,
        float* __restrict__ o_half, float* __restrict__ ms,
        float* __restrict__ ss) {
    const int bid = blockIdx.x;
    const int sel = bid % 3;
    if (sel == 2) {
        proj4_body(x, wv_m, vnew, bid / 3);
        return;
    }
    attn_body(q, kc, vc, o_half, ms, ss, (bid / 3) * 2 + sel);
}

// ---------------------------------------------------------------------------
// Fused out-projection: X_eff[b][col] = 2-way softmax merge of the key-half
// partials + vnew, reconstructed inline (all inputs L2/L3-resident, scalars
// wave-uniform per 32-lane half). Then the standard 8-row GEMV.
// out = X_eff @ Wo^T.
// ---------------------------------------------------------------------------
__device__ __forceinline__ f32x4 load_xeff(const float* __restrict__ o_half,
                                           const float* __restrict__ ms,
                                           const float* __restrict__ ss,
                                           const float* __restrict__ vnew,
                                           int row, int col) {
    const int h = col >> 7, d = col & 127;
    const int bh = row * NHEADS + h;
    const float m0 = ms[2 * bh], m1 = ms[2 * bh + 1];
    const float s0 = ss[2 * bh], s1 = ss[2 * bh + 1];
    const float M = fmaxf(m0, m1);
    const float w0 = __expf(m0 - M), w1 = __expf(m1 - M);
    const float inv = 1.0f / (s0 * w0 + s1 * w1);
    f32x4 o0 = *(const f32x4*)(o_half + (size_t)(2 * bh) * HDIM + d);
    f32x4 o1 = *(const f32x4*)(o_half + (size_t)(2 * bh + 1) * HDIM + d);
    f32x4 vn = *(const f32x4*)(vnew + (size_t)row * HIDDEN + col);
    return (o0 * w0 + o1 * w1) * inv + vn;
}

__global__ __launch_bounds__(512, 2) void proj_out_fused_kernel(
        const float* __restrict__ o_half, const float* __restrict__ ms,
        const float* __restrict__ ss, const float* __restrict__ vnew,
        const float* __restrict__ W, float* __restrict__ Y) {
    const int t   = threadIdx.x;
    const int l   = t & 63;
    const int wid = t >> 6;                      // 0..7 -> batch quartet
    const int rowbase = blockIdx.x * 8;
    const float* wp = W + (size_t)rowbase * HIDDEN + 4 * l;
    const int col0 = 4 * l;

    float v[32];
    #pragma unroll
    for (int j = 0; j < 32; ++j) v[j] = 0.f;

    #pragma unroll 2
    for (int kp = 0; kp < HIDDEN; kp += 256) {
        f32x4 wv[8], xv[4];
        #pragma unroll
        for (int r = 0; r < 8; ++r)
            wv[r] = *(const f32x4*)(wp + (size_t)r * HIDDEN + kp);
        #pragma unroll
        for (int b = 0; b < 4; ++b)
            xv[b] = load_xeff(o_half, ms, ss, vnew, wid * 4 + b, col0 + kp);
        #pragma unroll
        for (int r = 0; r < 8; ++r) {
            #pragma unroll
            for (int b = 0; b < 4; ++b) {
                v[r * 4 + b] += wv[r].x * xv[b].x + wv[r].y * xv[b].y +
                                wv[r].z * xv[b].z + wv[r].w * xv[b].w;
            }
        }
    }

    #pragma unroll
    for (int j = 0; j < 32; ++j) v[j] += __shfl_xor(v[j], 1);
    #pragma unroll
    for (int s = 1; s <= 5; ++s) {
        const int m = 1 << s;
        const int bit = (l >> s) & 1;
        #pragma unroll
        for (int i = 0; i < (32 >> s); ++i) {
            float t0 = __shfl_xor(v[2 * i], m);
            float t1 = __shfl_xor(v[2 * i + 1], m);
            v[i] = bit ? (v[2 * i + 1] + t1) : (v[2 * i] + t0);
        }
    }
    if (!(l & 1)) {
        const int j = l >> 1;
        const int r = j >> 2, b = j & 3;
        Y[(size_t)(wid * 4 + b) * HIDDEN + rowbase + r] = v[0];
    }
}

extern "C" void kernel_launch(void* const* d_in, const int* in_sizes, int n_in,
                              void* d_out, int out_size, void* d_ws, size_t ws_size,
                              hipStream_t stream) {
    (void)in_sizes; (void)n_in; (void)out_size; (void)ws_size;
    const float* x  = (const float*)d_in[0];
    const float* kc = (const float*)d_in[1];
    const float* vc = (const float*)d_in[2];
    const float* wq = (const float*)d_in[3];
    // d_in[4] (wk) unused: softmax over a single new key is exactly 1.0
    const float* wv = (const float*)d_in[5];
    const float* wo = (const float*)d_in[6];
    float* out = (float*)d_out;

    float* q      = (float*)d_ws;                        // 131072 floats
    float* vnew   = q + BATCH * HIDDEN;                  // 131072
    float* o_half = vnew + BATCH * HIDDEN;               // 2048*128
    float* ms     = o_half + 2 * BATCH * NHEADS * HDIM;  // 2048
    float* ss     = ms + 2 * BATCH * NHEADS;             // 2048

    proj_q_kernel<<<HIDDEN / 4, 256, 0, stream>>>(x, wq, q);
    attn_projv_kernel<<<3072, 256, 0, stream>>>(q, kc, vc, x, wv, vnew,
                                                o_half, ms, ss);
    proj_out_fused_kernel<<<HIDDEN / 8, 512, 0, stream>>>(o_half, ms, ss, vnew, wo, out);
}

// Round 9
// 200.769 us; speedup vs baseline: 1.1307x; 1.1307x over previous
//
#include <hip/hip_runtime.h>
#include <hip/hip_bf16.h>

#define HIDDEN 4096
#define NHEADS 32
#define HDIM 128
#define CLEN 512
#define BATCH 32

typedef float f32x4 __attribute__((ext_vector_type(4)));

// ---------------------------------------------------------------------------
// 4-row / 256-thread projection body (standalone q-proj).
// ---------------------------------------------------------------------------
__device__ __forceinline__ void proj4_body(const float* __restrict__ X,
                                           const float* __restrict__ W,
                                           float* __restrict__ Y,
                                           int rowblock) {
    const int t   = threadIdx.x;
    const int l   = t & 63;
    const int wid = t >> 6;                      // 0..3 -> batch octet
    const int rowbase = rowblock * 4;
    const float* wp = W + (size_t)rowbase * HIDDEN + 4 * l;
    const float* xp = X + (size_t)(wid * 8) * HIDDEN + 4 * l;

    float v[32];
    #pragma unroll
    for (int j = 0; j < 32; ++j) v[j] = 0.f;

    #pragma unroll 2
    for (int kp = 0; kp < HIDDEN; kp += 256) {
        float4 wv[4], xv[8];
        #pragma unroll
        for (int r = 0; r < 4; ++r)
            wv[r] = *(const float4*)(wp + (size_t)r * HIDDEN + kp);
        #pragma unroll
        for (int b = 0; b < 8; ++b)
            xv[b] = *(const float4*)(xp + (size_t)b * HIDDEN + kp);
        #pragma unroll
        for (int r = 0; r < 4; ++r) {
            #pragma unroll
            for (int b = 0; b < 8; ++b) {
                v[r * 8 + b] += wv[r].x * xv[b].x + wv[r].y * xv[b].y +
                                wv[r].z * xv[b].z + wv[r].w * xv[b].w;
            }
        }
    }

    #pragma unroll
    for (int j = 0; j < 32; ++j) v[j] += __shfl_xor(v[j], 1);
    #pragma unroll
    for (int s = 1; s <= 5; ++s) {
        const int m = 1 << s;
        const int bit = (l >> s) & 1;
        #pragma unroll
        for (int i = 0; i < (32 >> s); ++i) {
            float t0 = __shfl_xor(v[2 * i], m);
            float t1 = __shfl_xor(v[2 * i + 1], m);
            v[i] = bit ? (v[2 * i + 1] + t1) : (v[2 * i] + t0);
        }
    }
    if (!(l & 1)) {
        const int j = l >> 1;                    // 0..31
        const int r = j >> 3, b = j & 7;
        Y[(size_t)(wid * 8 + b) * HIDDEN + rowbase + r] = v[0];
    }
}

__global__ __launch_bounds__(256) void proj_q_kernel(const float* __restrict__ X,
                                                     const float* __restrict__ W,
                                                     float* __restrict__ Y) {
    proj4_body(X, W, Y, blockIdx.x);
}

// ---------------------------------------------------------------------------
// 8-row / 512-thread projection body (v-proj fused into attn dispatch).
// ---------------------------------------------------------------------------
__device__ __forceinline__ void proj8_body(const float* __restrict__ X,
                                           const float* __restrict__ W,
                                           float* __restrict__ Y,
                                           int rowblock) {
    const int t   = threadIdx.x;
    const int l   = t & 63;
    const int wid = t >> 6;                      // 0..7 -> batch quartet
    const int rowbase = rowblock * 8;
    const float* wp = W + (size_t)rowbase * HIDDEN + 4 * l;
    const float* xp = X + (size_t)(wid * 4) * HIDDEN + 4 * l;

    float v[32];
    #pragma unroll
    for (int j = 0; j < 32; ++j) v[j] = 0.f;

    #pragma unroll 2
    for (int kp = 0; kp < HIDDEN; kp += 256) {
        float4 wv[8], xv[4];
        #pragma unroll
        for (int r = 0; r < 8; ++r)
            wv[r] = *(const float4*)(wp + (size_t)r * HIDDEN + kp);
        #pragma unroll
        for (int b = 0; b < 4; ++b)
            xv[b] = *(const float4*)(xp + (size_t)b * HIDDEN + kp);
        #pragma unroll
        for (int r = 0; r < 8; ++r) {
            #pragma unroll
            for (int b = 0; b < 4; ++b) {
                v[r * 4 + b] += wv[r].x * xv[b].x + wv[r].y * xv[b].y +
                                wv[r].z * xv[b].z + wv[r].w * xv[b].w;
            }
        }
    }

    #pragma unroll
    for (int j = 0; j < 32; ++j) v[j] += __shfl_xor(v[j], 1);
    #pragma unroll
    for (int s = 1; s <= 5; ++s) {
        const int m = 1 << s;
        const int bit = (l >> s) & 1;
        #pragma unroll
        for (int i = 0; i < (32 >> s); ++i) {
            float t0 = __shfl_xor(v[2 * i], m);
            float t1 = __shfl_xor(v[2 * i + 1], m);
            v[i] = bit ? (v[2 * i + 1] + t1) : (v[2 * i] + t0);
        }
    }
    if (!(l & 1)) {
        const int j = l >> 1;
        const int r = j >> 2, b = j & 3;
        Y[(size_t)(wid * 4 + b) * HIDDEN + rowbase + r] = v[0];
    }
}

// ---------------------------------------------------------------------------
// Attention for ONE (b,h), 512 threads = 8 waves, STREAM-CONSOLIDATED:
// at round r the 8 waves read 16 CONSECUTIVE K rows (8 KB contiguous) and
// the matching V rows -> one sequential K stream + one V stream per block
// (vs 8 disjoint streams before). Wave-local online softmax (64 keys/wave
// via half-wave parity), then a single 8-wave LDS merge producing the FINAL
// normalized output (no separate combine kernel).
// key map: k = r*16 + w*2 + kh, r=0..31  -> covers 0..511 exactly once.
// ---------------------------------------------------------------------------
__device__ __forceinline__ void attn_body(const float* __restrict__ q,
                                          const float* __restrict__ kc,
                                          const float* __restrict__ vc,
                                          float* __restrict__ attn_out,  // [32][4096] normalized, no vnew
                                          int bh) {
    __shared__ float lo[8][HDIM];
    __shared__ float lm[8], lsw[8];
    const int t = threadIdx.x;
    const int w = t >> 6;                 // wave 0..7
    const int l = t & 63;
    const int b = bh >> 5, h = bh & 31;
    const float* K = kc + (size_t)bh * CLEN * HDIM;
    const float* V = vc + (size_t)bh * CLEN * HDIM;
    const float scale = 0.088388347648318447f;   // 1/sqrt(128)
    const int d0 = 4 * (l & 31);
    const int kh = l >> 5;                // half-wave key parity
    f32x4 q4 = *(const f32x4*)(q + (size_t)b * HIDDEN + h * HDIM + d0);

    float mloc = -INFINITY, sloc = 0.f;
    f32x4 acc = {0.f, 0.f, 0.f, 0.f};

    #pragma unroll 4
    for (int r = 0; r < 32; ++r) {
        const int k = r * 16 + w * 2 + kh;
        f32x4 kv = __builtin_nontemporal_load((const f32x4*)(K + (size_t)k * HDIM + d0));
        float p = q4.x * kv.x + q4.y * kv.y + q4.z * kv.z + q4.w * kv.w;
        #pragma unroll
        for (int m = 16; m; m >>= 1) p += __shfl_xor(p, m);  // 32-lane halves
        p *= scale;
        f32x4 vv = __builtin_nontemporal_load((const f32x4*)(V + (size_t)k * HDIM + d0));
        const float mn = fmaxf(mloc, p);
        const float c = __expf(mloc - mn);   // 0 on first round (mloc=-inf)
        const float e = __expf(p - mn);
        sloc = sloc * c + e;
        acc = acc * c + vv * e;
        mloc = mn;
    }

    // ---- merge the two half-wave streams (even vs odd keys) ----
    const float mo = __shfl_xor(mloc, 32);
    const float M = fmaxf(mloc, mo);
    const float wsc = __expf(mloc - M);
    float sw = sloc * wsc;
    sw += __shfl_xor(sw, 32);
    acc *= wsc;
    acc.x += __shfl_xor(acc.x, 32);
    acc.y += __shfl_xor(acc.y, 32);
    acc.z += __shfl_xor(acc.z, 32);
    acc.w += __shfl_xor(acc.w, 32);

    // ---- 8-wave LDS merge -> final normalized output ----
    if (l < 32) *(f32x4*)(&lo[w][d0]) = acc;
    if (l == 0) { lm[w] = M; lsw[w] = sw; }
    __syncthreads();
    if (t < HDIM) {
        float M8 = lm[0];
        #pragma unroll
        for (int j = 1; j < 8; ++j) M8 = fmaxf(M8, lm[j]);
        float o = 0.f, ssum = 0.f;
        #pragma unroll
        for (int j = 0; j < 8; ++j) {
            const float ej = __expf(lm[j] - M8);
            o += lo[j][t] * ej;
            ssum += lsw[j] * ej;
        }
        attn_out[(size_t)b * HIDDEN + h * HDIM + t] = o / ssum;
    }
}

// ---------------------------------------------------------------------------
// Fused dispatch: 1536 blocks of 512 threads. bid%3==2 -> v-proj chunk
// (512 blocks, 8 rows each); else attention head (1024). Interleaved so
// proj blocks stay co-resident with attn blocks throughout.
// ---------------------------------------------------------------------------
__global__ __launch_bounds__(512, 4) void attn_projv_kernel(
        const float* __restrict__ q, const float* __restrict__ kc,
        const float* __restrict__ vc, const float* __restrict__ x,
        const float* __restrict__ wv_m, float* __restrict__ vnew,
        float* __restrict__ attn_out) {
    const int bid = blockIdx.x;
    const int sel = bid % 3;
    if (sel == 2) {
        proj8_body(x, wv_m, vnew, bid / 3);
        return;
    }
    attn_body(q, kc, vc, attn_out, (bid / 3) * 2 + sel);
}

// ---------------------------------------------------------------------------
// Out-projection with cheap fused add: X_eff = attn_final + vnew
// (2 vector loads + add per element; both L2/L3-resident).
// ---------------------------------------------------------------------------
__global__ __launch_bounds__(512, 2) void proj_out_kernel(
        const float* __restrict__ Xa, const float* __restrict__ Xb,
        const float* __restrict__ W, float* __restrict__ Y) {
    const int t   = threadIdx.x;
    const int l   = t & 63;
    const int wid = t >> 6;                      // 0..7 -> batch quartet
    const int rowbase = blockIdx.x * 8;
    const float* wp = W + (size_t)rowbase * HIDDEN + 4 * l;
    const int col0 = 4 * l;

    float v[32];
    #pragma unroll
    for (int j = 0; j < 32; ++j) v[j] = 0.f;

    #pragma unroll 2
    for (int kp = 0; kp < HIDDEN; kp += 256) {
        f32x4 wv[8], xv[4];
        #pragma unroll
        for (int r = 0; r < 8; ++r)
            wv[r] = *(const f32x4*)(wp + (size_t)r * HIDDEN + kp);
        #pragma unroll
        for (int b = 0; b < 4; ++b) {
            const size_t off = (size_t)(wid * 4 + b) * HIDDEN + col0 + kp;
            xv[b] = *(const f32x4*)(Xa + off) + *(const f32x4*)(Xb + off);
        }
        #pragma unroll
        for (int r = 0; r < 8; ++r) {
            #pragma unroll
            for (int b = 0; b < 4; ++b) {
                v[r * 4 + b] += wv[r].x * xv[b].x + wv[r].y * xv[b].y +
                                wv[r].z * xv[b].z + wv[r].w * xv[b].w;
            }
        }
    }

    #pragma unroll
    for (int j = 0; j < 32; ++j) v[j] += __shfl_xor(v[j], 1);
    #pragma unroll
    for (int s = 1; s <= 5; ++s) {
        const int m = 1 << s;
        const int bit = (l >> s) & 1;
        #pragma unroll
        for (int i = 0; i < (32 >> s); ++i) {
            float t0 = __shfl_xor(v[2 * i], m);
            float t1 = __shfl_xor(v[2 * i + 1], m);
            v[i] = bit ? (v[2 * i + 1] + t1) : (v[2 * i] + t0);
        }
    }
    if (!(l & 1)) {
        const int j = l >> 1;
        const int r = j >> 2, b = j & 3;
        Y[(size_t)(wid * 4 + b) * HIDDEN + rowbase + r] = v[0];
    }
}

extern "C" void kernel_launch(void* const* d_in, const int* in_sizes, int n_in,
                              void* d_out, int out_size, void* d_ws, size_t ws_size,
                              hipStream_t stream) {
    (void)in_sizes; (void)n_in; (void)out_size; (void)ws_size;
    const float* x  = (const float*)d_in[0];
    const float* kc = (const float*)d_in[1];
    const float* vc = (const float*)d_in[2];
    const float* wq = (const float*)d_in[3];
    // d_in[4] (wk) unused: softmax over a single new key is exactly 1.0
    const float* wv = (const float*)d_in[5];
    const float* wo = (const float*)d_in[6];
    float* out = (float*)d_out;

    float* q    = (float*)d_ws;                  // 32*4096 fp32
    float* vnew = q + BATCH * HIDDEN;            // 32*4096
    float* attn = vnew + BATCH * HIDDEN;         // 32*4096 (normalized, no vnew)

    proj_q_kernel<<<HIDDEN / 4, 256, 0, stream>>>(x, wq, q);
    attn_projv_kernel<<<1536, 512, 0, stream>>>(q, kc, vc, x, wv, vnew, attn);
    proj_out_kernel<<<HIDDEN / 8, 512, 0, stream>>>(attn, vnew, wo, out);
}

// Round 10
// 184.299 us; speedup vs baseline: 1.2318x; 1.0894x over previous
//
#include <hip/hip_runtime.h>
#include <hip/hip_bf16.h>

#define HIDDEN 4096
#define NHEADS 32
#define HDIM 128
#define CLEN 512
#define BATCH 32
#define KB 256   // keys per attention half-block (4 waves x 64 keys)

typedef float f32x4 __attribute__((ext_vector_type(4)));

// ---------------------------------------------------------------------------
// 8-row / 512-thread projection body: coalesced W streaming + butterfly
// reduction. Used for standalone q-proj AND out-proj (both measured ~13 us
// per 64 MB weight stream; halves L2 x re-read traffic vs the 4-row form).
// ---------------------------------------------------------------------------
__device__ __forceinline__ void proj_body(const float* __restrict__ X,
                                          const float* __restrict__ W,
                                          float* __restrict__ Y,
                                          int rowblock) {
    const int t   = threadIdx.x;
    const int l   = t & 63;
    const int wid = t >> 6;                      // 0..7 -> batch quartet
    const int rowbase = rowblock * 8;
    const float* wp = W + (size_t)rowbase * HIDDEN + 4 * l;
    const float* xp = X + (size_t)(wid * 4) * HIDDEN + 4 * l;

    float v[32];
    #pragma unroll
    for (int j = 0; j < 32; ++j) v[j] = 0.f;

    #pragma unroll 2
    for (int kp = 0; kp < HIDDEN; kp += 256) {
        float4 wv[8], xv[4];
        #pragma unroll
        for (int r = 0; r < 8; ++r)
            wv[r] = *(const float4*)(wp + (size_t)r * HIDDEN + kp);
        #pragma unroll
        for (int b = 0; b < 4; ++b)
            xv[b] = *(const float4*)(xp + (size_t)b * HIDDEN + kp);
        #pragma unroll
        for (int r = 0; r < 8; ++r) {
            #pragma unroll
            for (int b = 0; b < 4; ++b) {
                v[r * 4 + b] += wv[r].x * xv[b].x + wv[r].y * xv[b].y +
                                wv[r].z * xv[b].z + wv[r].w * xv[b].w;
            }
        }
    }

    #pragma unroll
    for (int j = 0; j < 32; ++j) v[j] += __shfl_xor(v[j], 1);
    #pragma unroll
    for (int s = 1; s <= 5; ++s) {
        const int m = 1 << s;
        const int bit = (l >> s) & 1;
        #pragma unroll
        for (int i = 0; i < (32 >> s); ++i) {
            float t0 = __shfl_xor(v[2 * i], m);
            float t1 = __shfl_xor(v[2 * i + 1], m);
            v[i] = bit ? (v[2 * i + 1] + t1) : (v[2 * i] + t0);
        }
    }
    if (!(l & 1)) {
        const int j = l >> 1;
        const int r = j >> 2, b = j & 3;
        Y[(size_t)(wid * 4 + b) * HIDDEN + rowbase + r] = v[0];
    }
}

__global__ __launch_bounds__(512, 2) void proj_q_kernel(const float* __restrict__ X,
                                                        const float* __restrict__ W,
                                                        float* __restrict__ Y) {
    proj_body(X, W, Y, blockIdx.x);
}

__global__ __launch_bounds__(512, 2) void proj_out_kernel(const float* __restrict__ X,
                                                          const float* __restrict__ W,
                                                          float* __restrict__ Y) {
    proj_body(X, W, Y, blockIdx.x);
}

// ---------------------------------------------------------------------------
// 4-row / 256-thread projection body (v-proj fused into the 256-thread
// attention dispatch).
// ---------------------------------------------------------------------------
__device__ __forceinline__ void proj4_body(const float* __restrict__ X,
                                           const float* __restrict__ W,
                                           float* __restrict__ Y,
                                           int rowblock) {
    const int t   = threadIdx.x;
    const int l   = t & 63;
    const int wid = t >> 6;                      // 0..3 -> batch octet
    const int rowbase = rowblock * 4;
    const float* wp = W + (size_t)rowbase * HIDDEN + 4 * l;
    const float* xp = X + (size_t)(wid * 8) * HIDDEN + 4 * l;

    float v[32];
    #pragma unroll
    for (int j = 0; j < 32; ++j) v[j] = 0.f;

    #pragma unroll 2
    for (int kp = 0; kp < HIDDEN; kp += 256) {
        float4 wv[4], xv[8];
        #pragma unroll
        for (int r = 0; r < 4; ++r)
            wv[r] = *(const float4*)(wp + (size_t)r * HIDDEN + kp);
        #pragma unroll
        for (int b = 0; b < 8; ++b)
            xv[b] = *(const float4*)(xp + (size_t)b * HIDDEN + kp);
        #pragma unroll
        for (int r = 0; r < 4; ++r) {
            #pragma unroll
            for (int b = 0; b < 8; ++b) {
                v[r * 8 + b] += wv[r].x * xv[b].x + wv[r].y * xv[b].y +
                                wv[r].z * xv[b].z + wv[r].w * xv[b].w;
            }
        }
    }

    #pragma unroll
    for (int j = 0; j < 32; ++j) v[j] += __shfl_xor(v[j], 1);
    #pragma unroll
    for (int s = 1; s <= 5; ++s) {
        const int m = 1 << s;
        const int bit = (l >> s) & 1;
        #pragma unroll
        for (int i = 0; i < (32 >> s); ++i) {
            float t0 = __shfl_xor(v[2 * i], m);
            float t1 = __shfl_xor(v[2 * i + 1], m);
            v[i] = bit ? (v[2 * i + 1] + t1) : (v[2 * i] + t0);
        }
    }
    if (!(l & 1)) {
        const int j = l >> 1;                    // 0..31
        const int r = j >> 3, b = j & 7;
        Y[(size_t)(wid * 8 + b) * HIDDEN + rowbase + r] = v[0];
    }
}

// ---------------------------------------------------------------------------
// Attention: fully wave-local online-softmax flash. Zero LDS, zero barriers.
// Each wave owns a contiguous 64-key slice (32 KB K + 32 KB V walk): per
// round (2 keys via half-wave split) load K row pair -> butterfly score ->
// online (m,s,acc) update -> V row pair accumulate. Per-wave partials
// (8 per bh) merged exactly in combine_kernel.
// ---------------------------------------------------------------------------
__device__ __forceinline__ void attn_body(const float* __restrict__ q,
                                          const float* __restrict__ kc,
                                          const float* __restrict__ vc,
                                          float* __restrict__ o_part,   // [8192][128]
                                          float* __restrict__ ms,       // [8192]
                                          float* __restrict__ ss,       // [8192]
                                          int bid) {
    const int t = threadIdx.x;
    const int w = t >> 6;                 // wave 0..3
    const int l = t & 63;
    const int bh = bid >> 1;
    const int half = bid & 1;
    const int b = bh >> 5, h = bh & 31;
    const float* K = kc + (size_t)bh * CLEN * HDIM + (size_t)(half * KB + w * 64) * HDIM;
    const float* V = vc + (size_t)bh * CLEN * HDIM + (size_t)(half * KB + w * 64) * HDIM;
    const float scale = 0.088388347648318447f;   // 1/sqrt(128)
    const int d0 = 4 * (l & 31);
    const int kh = l >> 5;                // half-wave key parity
    const int rot = (bid & 31) * 2;       // even stagger within the 64 keys
    f32x4 q4 = *(const f32x4*)(q + (size_t)b * HIDDEN + h * HDIM + d0);

    float mloc = -INFINITY, sloc = 0.f;
    f32x4 acc = {0.f, 0.f, 0.f, 0.f};

    #pragma unroll 4
    for (int r = 0; r < 32; ++r) {
        const int k = ((2 * r + rot) & 63) + kh;
        f32x4 kv = __builtin_nontemporal_load((const f32x4*)(K + (size_t)k * HDIM + d0));
        float p = q4.x * kv.x + q4.y * kv.y + q4.z * kv.z + q4.w * kv.w;
        #pragma unroll
        for (int m = 16; m; m >>= 1) p += __shfl_xor(p, m);  // 32-lane halves
        p *= scale;
        f32x4 vv = __builtin_nontemporal_load((const f32x4*)(V + (size_t)k * HDIM + d0));
        const float mn = fmaxf(mloc, p);
        const float c = __expf(mloc - mn);   // 0 on first round (mloc=-inf)
        const float e = __expf(p - mn);
        sloc = sloc * c + e;
        acc = acc * c + vv * e;
        mloc = mn;
    }

    // ---- merge the two half-wave streams (even vs odd keys) ----
    const float mo = __shfl_xor(mloc, 32);
    const float M = fmaxf(mloc, mo);
    const float wsc = __expf(mloc - M);
    float sw = sloc * wsc;
    sw += __shfl_xor(sw, 32);
    acc *= wsc;
    acc.x += __shfl_xor(acc.x, 32);
    acc.y += __shfl_xor(acc.y, 32);
    acc.z += __shfl_xor(acc.z, 32);
    acc.w += __shfl_xor(acc.w, 32);

    const int pid = bh * 8 + half * 4 + w;
    if (l < 32) *(f32x4*)(o_part + (size_t)pid * HDIM + d0) = acc;
    if (l == 0) { ms[pid] = M; ss[pid] = sw; }
}

// ---------------------------------------------------------------------------
// Fused dispatch: 3072 blocks. bid%3==2 -> v-projection chunk (1024 blocks);
// else attention half-block (2048). proj_v rides in attention's BW slack.
// ---------------------------------------------------------------------------
__global__ __launch_bounds__(256, 4) void attn_projv_kernel(
        const float* __restrict__ q, const float* __restrict__ kc,
        const float* __restrict__ vc, const float* __restrict__ x,
        const float* __restrict__ wv_m, float* __restrict__ vnew,
        float* __restrict__ o_part, float* __restrict__ ms,
        float* __restrict__ ss) {
    const int bid = blockIdx.x;
    const int sel = bid % 3;
    if (sel == 2) {
        proj4_body(x, wv_m, vnew, bid / 3);
        return;
    }
    attn_body(q, kc, vc, o_part, ms, ss, (bid / 3) * 2 + sel);
}

// ---------------------------------------------------------------------------
// Exact 8-way softmax merge + v_new add.
// out[bh][d] = sum_j o_j[d] w_j / sum_j s_j w_j + vnew,  w_j = exp(m_j - M).
// ---------------------------------------------------------------------------
__global__ __launch_bounds__(256) void combine_kernel(
        const float* __restrict__ o_part,
        const float* __restrict__ ms,
        const float* __restrict__ ss,
        const float* __restrict__ vnew,   // [32][4096]
        float* __restrict__ attn_out) {   // [32][4096]
    const int t = threadIdx.x;
    const int bh = blockIdx.x * 2 + (t >> 7);
    const int d = t & 127;
    float m[8];
    #pragma unroll
    for (int j = 0; j < 8; ++j) m[j] = ms[bh * 8 + j];
    float M = m[0];
    #pragma unroll
    for (int j = 1; j < 8; ++j) M = fmaxf(M, m[j]);
    float ssum = 0.f, o = 0.f;
    #pragma unroll
    for (int j = 0; j < 8; ++j) {
        const float wj = __expf(m[j] - M);
        ssum += ss[bh * 8 + j] * wj;
        o += o_part[(size_t)(bh * 8 + j) * HDIM + d] * wj;
    }
    const int b = bh >> 5, h = bh & 31;
    const size_t idx = (size_t)b * HIDDEN + h * HDIM + d;
    attn_out[idx] = o / ssum + vnew[idx];
}

extern "C" void kernel_launch(void* const* d_in, const int* in_sizes, int n_in,
                              void* d_out, int out_size, void* d_ws, size_t ws_size,
                              hipStream_t stream) {
    (void)in_sizes; (void)n_in; (void)out_size; (void)ws_size;
    const float* x  = (const float*)d_in[0];
    const float* kc = (const float*)d_in[1];
    const float* vc = (const float*)d_in[2];
    const float* wq = (const float*)d_in[3];
    // d_in[4] (wk) unused: softmax over a single new key is exactly 1.0
    const float* wv = (const float*)d_in[5];
    const float* wo = (const float*)d_in[6];
    float* out = (float*)d_out;

    float* q      = (float*)d_ws;                        // 131072 floats
    float* vnew   = q + BATCH * HIDDEN;                  // 131072
    float* attn   = vnew + BATCH * HIDDEN;               // 131072
    float* o_part = attn + BATCH * HIDDEN;               // 8192*128
    float* ms     = o_part + 8 * BATCH * NHEADS * HDIM;  // 8192
    float* ss     = ms + 8 * BATCH * NHEADS;             // 8192

    proj_q_kernel<<<HIDDEN / 8, 512, 0, stream>>>(x, wq, q);
    attn_projv_kernel<<<3072, 256, 0, stream>>>(q, kc, vc, x, wv, vnew,
                                                o_part, ms, ss);
    combine_kernel<<<BATCH * NHEADS / 2, 256, 0, stream>>>(o_part, ms, ss, vnew, attn);
    proj_out_kernel<<<HIDDEN / 8, 512, 0, stream>>>(attn, wo, out);
}